// Round 4
// baseline (3605.328 us; speedup 1.0000x reference)
//
#include <hip/hip_runtime.h>

// SGLC encoder on MI355X: T=64, B=32, N=64, DIN=H=128, 2 layers, dynamic supports.
// One workgroup per batch chain (32 blocks x 1024 thr), bf16 MFMA 32x32x16,
// fragment-packed weights streamed from L2, all activations in LDS.
// v2: fp32 h master in LDS (sHf).
// v4: u gate fp32 in LDS; Wq/Wk preload dropped; final-h store hoisted.
// v5: - single accumulator pair A0/A1 reused across all GEMM phases
//       (32 AGPRs instead of 64 -> headroom for load pipelining, no spill)
//     - M = Wq@Wk^T precomputed (scores = h@M@h^T): P5 halves to one g=h@M
//       GEMM, P6 reads sHb directly, sK eliminated
//     - r*h uses fp32 h from sHf
#define TT 64
#define BB 32
#define NN 64
#define HH 128
#define NH 8192

using short8 = __attribute__((ext_vector_type(8))) short;
using f32x16 = __attribute__((ext_vector_type(16))) float;

__device__ __forceinline__ unsigned short f2bf(float f) {
  unsigned int u = __float_as_uint(f);
  u = (u + 0x7FFFu + ((u >> 16) & 1u)) >> 16;
  return (unsigned short)u;
}
__device__ __forceinline__ float bf2f(unsigned short s) {
  return __uint_as_float(((unsigned int)s) << 16);
}
__device__ __forceinline__ float sigm(float x) { return 1.0f / (1.0f + __expf(-x)); }
__device__ __forceinline__ float tanh_fast(float x) { return 2.0f / (1.0f + __expf(-2.0f * x)) - 1.0f; }

__device__ __forceinline__ uint2 pack4(float a, float b, float c, float d) {
  uint2 r;
  r.x = (unsigned int)f2bf(a) | ((unsigned int)f2bf(b) << 16);
  r.y = (unsigned int)f2bf(c) | ((unsigned int)f2bf(d) << 16);
  return r;
}
// LDS fragment load: 8 bf16 at 8B-aligned address
__device__ __forceinline__ short8 ldsfrag(const unsigned short* p) {
  union { uint2 u2[2]; short8 s; } f;
  f.u2[0] = *(const uint2*)p;
  f.u2[1] = *(const uint2*)(p + 4);
  return f.s;
}
// Global fragment load: 16B coalesced from fragment-packed weights
__device__ __forceinline__ short8 ldgfrag(const unsigned short* p) {
  union { uint4 u4; short8 s; } f;
  f.u4 = *(const uint4*)p;
  return f.s;
}

// ---- weight packing: fp32 W[k][c] -> bf16 fragment-major blocks of 512 ushorts per (c32,kc):
// packed[((c32*nkc + kc)<<9) + lane*8 + j] = bf16(W[kc*16 + (lane>>5)*8 + j][c32*32 + (lane&31)])
// Regions per layer (ushort offsets): Wg 0 (nkc=32,ncols=256), Wc 131072 (32,128),
//   M=Wq@Wk^T 196608 (nkc=8,ncols=128)  [written by sglc_packM after sglc_pack]
__global__ void sglc_pack(const float* __restrict__ Wg0, const float* __restrict__ Wc0,
                          const float* __restrict__ Wq0, const float* __restrict__ Wk0,
                          const float* __restrict__ Wg1, const float* __restrict__ Wc1,
                          const float* __restrict__ Wq1, const float* __restrict__ Wk1,
                          unsigned short* __restrict__ dst) {
  int idx = blockIdx.x * 256 + threadIdx.x;
  if (idx >= 458752) return;
  int layer = idx / 229376;
  int lo = idx - layer * 229376;
  const float* src; int nkc, ncshift, off;
  if (lo < 131072)      { src = layer ? Wg1 : Wg0; nkc = 32; ncshift = 8; off = 0; }
  else if (lo < 196608) { src = layer ? Wc1 : Wc0; nkc = 32; ncshift = 7; off = 131072; }
  else if (lo < 212992) { src = layer ? Wq1 : Wq0; nkc = 8;  ncshift = 7; off = 196608; }
  else                  { src = layer ? Wk1 : Wk0; nkc = 8;  ncshift = 7; off = 212992; }
  int l2 = lo - off;
  int k = l2 >> ncshift;
  int c = l2 & ((1 << ncshift) - 1);
  int c32 = c >> 5, n32 = c & 31;
  int kc = k >> 4, kl = k & 15;
  int half = kl >> 3, j = kl & 7;
  int lane = half * 32 + n32;
  int dstoff = layer * 229376 + off + (((c32 * nkc + kc) << 9) + lane * 8 + j);
  dst[dstoff] = f2bf(src[(size_t)k * (1 << ncshift) + c]);
}

// ---- M = Wq @ Wk^T (fp32 dot over e=0..127), packed as B-fragments at region 196608.
// M[d][d'] = sum_e Wq[d][e]*Wk[d'][e];  g = h@M;  scores = g@h^T  (== (hWq)(hWk)^T)
__global__ void sglc_packM(const float* __restrict__ Wq0, const float* __restrict__ Wk0,
                           const float* __restrict__ Wq1, const float* __restrict__ Wk1,
                           unsigned short* __restrict__ dst) {
  int idx = blockIdx.x * 256 + threadIdx.x;  // 32768 total
  int layer = idx >> 14;
  int off = idx & 16383;
  int block = off >> 9;          // c32*8 + kc, 0..31
  int lane = (off >> 3) & 63;
  int j = off & 7;
  int c32 = block >> 3, kc = block & 7;
  int half = lane >> 5, n32 = lane & 31;
  int a = kc * 16 + half * 8 + j;      // M row (d)
  int bcol = c32 * 32 + n32;           // M col (d')
  const float* Q = layer ? Wq1 : Wq0;
  const float* K = layer ? Wk1 : Wk0;
  float s = 0.0f;
#pragma unroll 4
  for (int e = 0; e < 128; e += 4) {
    float4 qa = *(const float4*)(Q + a * 128 + e);
    float4 kb = *(const float4*)(K + bcol * 128 + e);
    s += qa.x * kb.x + qa.y * kb.y + qa.z * kb.z + qa.w * kb.w;
  }
  dst[layer * 229376 + 196608 + (block << 9) + lane * 8 + j] = f2bf(s);
}

// LDS layout (ushort offsets), all bf16 row stride 132 (A-arrays) / 68 (sup, PT):
#define SX_O   0
#define SH_O   8448
#define SRH_O  16896
#define SQ_O   25344
#define SK_O   33792
#define SSUP_O 42240
#define SPT_O  46592
#define LDS_USHORTS 64000      // 128000 bytes of bf16 buffers
#define SHF_BYTES 32768        // + 64x128 fp32 h master
#define LDS_BYTES (LDS_USHORTS * 2 + SHF_BYTES)  // 160768 <= 160 KiB

extern "C" __global__ void __launch_bounds__(1024, 4)
sglc_main(const float* __restrict__ Xin, const float* __restrict__ H0,
          const float* __restrict__ Sup0,
          const float* __restrict__ bg0, const float* __restrict__ bc0,
          const float* __restrict__ bg1, const float* __restrict__ bc1,
          const unsigned short* __restrict__ Wp, float* __restrict__ Out) {
  extern __shared__ unsigned short sm[];
  unsigned short* sX   = sm + SX_O;
  unsigned short* sHb  = sm + SH_O;
  unsigned short* sRH  = sm + SRH_O;
  unsigned short* sQ   = sm + SQ_O;
  unsigned short* sSup = sm + SSUP_O;
  unsigned short* sPT  = sm + SPT_O;
  float* sS  = (float*)(sm + SPT_O);        // overlays sPT (disjoint in time within a step)
  float* uS  = (float*)(sm + SQ_O);         // fp32 u gate, overlays sQ/sK (free P2->P5), 32 KB
  float* sHf = (float*)(sm + LDS_USHORTS);  // fp32 h master, stride 128 (bank = n32, conflict-free)

  const int b = blockIdx.x;
  const int tid = threadIdx.x;
  const int lane = tid & 63;
  const int w = tid >> 6;
  const int n32 = lane & 31;
  const int half = lane >> 5;
  const int kob = half * 8;

  float* OutH = Out;
  float* Cur  = Out + 2 * BB * NH;

  for (int layer = 0; layer < 2; ++layer) {
    const int Lw = layer * 229376;
    const float* bg = layer ? bg1 : bg0;
    const float* bc = layer ? bc1 : bc0;
    const float* xbase = layer ? Cur : Xin;
    const float* h0p = H0 + (size_t)(layer * BB + b) * NH;

    const float bgv = (w < 8) ? bg[(w & 7) * 32 + n32] : 0.0f;
    const float bcv = (w >= 4 && w < 8) ? bc[(w - 4) * 32 + n32] : 0.0f;

    // ---- layer init: stage h0 (bf16 + fp32 master), sup (layer 0), x_0 ----
    {
      int r = tid >> 4, c0 = (tid & 15) * 8;
      const float* hp = h0p + r * 128 + c0;
      float4 v0 = *(const float4*)(hp);
      float4 v1 = *(const float4*)(hp + 4);
      *(uint2*)(sHb + r * 132 + c0)     = pack4(v0.x, v0.y, v0.z, v0.w);
      *(uint2*)(sHb + r * 132 + c0 + 4) = pack4(v1.x, v1.y, v1.z, v1.w);
      *(float4*)(sHf + r * 128 + c0)     = v0;
      *(float4*)(sHf + r * 128 + c0 + 4) = v1;
      const float* xp = xbase + (size_t)(0 * BB + b) * NH + r * 128 + c0;
      float4 x0 = *(const float4*)(xp);
      float4 x1 = *(const float4*)(xp + 4);
      *(uint2*)(sX + r * 132 + c0)     = pack4(x0.x, x0.y, x0.z, x0.w);
      *(uint2*)(sX + r * 132 + c0 + 4) = pack4(x1.x, x1.y, x1.z, x1.w);
      if (layer == 0) {
        int rs = tid >> 4, cs = (tid & 15) * 4;
        float4 sv = *(const float4*)(Sup0 + (size_t)b * 4096 + rs * 64 + cs);
        *(uint2*)(sSup + rs * 68 + cs) = pack4(sv.x, sv.y, sv.z, sv.w);
      }
    }
    __syncthreads();

    for (int t = 0; t < TT; ++t) {
      f32x16 A0, A1;  // single accumulator pair, reused phase-to-phase (32 AGPRs)
#pragma unroll
      for (int z = 0; z < 16; ++z) { A0[z] = 0.0f; A1[z] = 0.0f; }

      // ===== gates GEMM: P1 = xh@Wg[0:256,:] (w0-7), P2 = xh@Wg[256:512,:] (w8-15) =====
      {
        const int c32g = w & 7;
        const unsigned short* wb = Wp + Lw + (((c32g * 32 + (w < 8 ? 0 : 16)) << 9) + lane * 8);
#pragma unroll
        for (int kc = 0; kc < 16; ++kc) {
          const unsigned short* asrc = (kc < 8) ? (sX + kc * 16 + kob) : (sHb + (kc - 8) * 16 + kob);
          short8 a0 = ldsfrag(asrc + n32 * 132);
          short8 a1 = ldsfrag(asrc + (32 + n32) * 132);
          short8 bf = ldgfrag(wb + (kc << 9));
          A0 = __builtin_amdgcn_mfma_f32_32x32x16_bf16(a0, bf, A0, 0, 0, 0);
          A1 = __builtin_amdgcn_mfma_f32_32x32x16_bf16(a1, bf, A1, 0, 0, 0);
        }
        if (w >= 8) {  // write P2^T (bf16) for the conv
          unsigned short* pb = sPT + (c32g * 32 + n32) * 68;
#pragma unroll
          for (int tt = 0; tt < 2; ++tt) {
            const f32x16& ac = tt ? A1 : A0;
#pragma unroll
            for (int g = 0; g < 4; ++g)
              *(uint2*)(pb + tt * 32 + 8 * g + 4 * half) =
                  pack4(ac[4 * g], ac[4 * g + 1], ac[4 * g + 2], ac[4 * g + 3]);
          }
        }
      }
      __syncthreads();  // B1

      // ===== conv r/u (w0-7): A += sup @ P2 =====
      if (w < 8) {
        const int c32g = w & 7;
#pragma unroll
        for (int kc2 = 0; kc2 < 4; ++kc2) {
          short8 a0 = ldsfrag(sSup + n32 * 68 + kc2 * 16 + kob);
          short8 a1 = ldsfrag(sSup + (32 + n32) * 68 + kc2 * 16 + kob);
          short8 bf = ldsfrag(sPT + (c32g * 32 + n32) * 68 + kc2 * 16 + kob);
          A0 = __builtin_amdgcn_mfma_f32_32x32x16_bf16(a0, bf, A0, 0, 0, 0);
          A1 = __builtin_amdgcn_mfma_f32_32x32x16_bf16(a1, bf, A1, 0, 0, 0);
        }
        if (w < 4) {  // r -> rh into sRH (bf16), h from fp32 master
          const int col = (w & 7) * 32 + n32;
#pragma unroll
          for (int tt = 0; tt < 2; ++tt) {
            const f32x16& ac = tt ? A1 : A0;
#pragma unroll
            for (int g = 0; g < 4; ++g)
#pragma unroll
              for (int i = 0; i < 4; ++i) {
                int row = tt * 32 + 8 * g + 4 * half + i;
                float rv = sigm(ac[4 * g + i] + bgv);
                float hv = sHf[row * 128 + col];
                sRH[row * 132 + col] = f2bf(rv * hv);
              }
          }
        } else {  // u -> fp32 LDS (sQ/sK region, free until P5)
          const int ucol = (w - 4) * 32 + n32;
#pragma unroll
          for (int tt = 0; tt < 2; ++tt) {
            const f32x16& ac = tt ? A1 : A0;
#pragma unroll
            for (int g = 0; g < 4; ++g)
#pragma unroll
              for (int i = 0; i < 4; ++i) {
                int row = tt * 32 + 8 * g + 4 * half + i;
                uS[row * 128 + ucol] = sigm(ac[4 * g + i] + bgv);
              }
          }
        }
      }
      __syncthreads();  // B2

      // ===== candidate GEMM: Q1 = xh_r@Wc[0:256] (w4-7), Q2 = xh_r@Wc[256:512] (w8-11) =====
      if (w >= 4 && w < 12) {
#pragma unroll
        for (int z = 0; z < 16; ++z) { A0[z] = 0.0f; A1[z] = 0.0f; }
        const int c32c = (w < 8) ? (w - 4) : (w - 8);
        const unsigned short* wb = Wp + Lw + 131072 + (((c32c * 32 + (w < 8 ? 0 : 16)) << 9) + lane * 8);
#pragma unroll
        for (int kc = 0; kc < 16; ++kc) {
          const unsigned short* asrc = (kc < 8) ? (sX + kc * 16 + kob) : (sRH + (kc - 8) * 16 + kob);
          short8 a0 = ldsfrag(asrc + n32 * 132);
          short8 a1 = ldsfrag(asrc + (32 + n32) * 132);
          short8 bf = ldgfrag(wb + (kc << 9));
          A0 = __builtin_amdgcn_mfma_f32_32x32x16_bf16(a0, bf, A0, 0, 0, 0);
          A1 = __builtin_amdgcn_mfma_f32_32x32x16_bf16(a1, bf, A1, 0, 0, 0);
        }
        if (w >= 8) {  // write Q2^T
          unsigned short* pb = sPT + (c32c * 32 + n32) * 68;
#pragma unroll
          for (int tt = 0; tt < 2; ++tt) {
            const f32x16& ac = tt ? A1 : A0;
#pragma unroll
            for (int g = 0; g < 4; ++g)
              *(uint2*)(pb + tt * 32 + 8 * g + 4 * half) =
                  pack4(ac[4 * g], ac[4 * g + 1], ac[4 * g + 2], ac[4 * g + 3]);
          }
        }
      }
      __syncthreads();  // B3

      // ===== conv c + h update (w4-7); x_{t+1} staging (w0-3, w12-15) =====
      if (w >= 4 && w < 8) {
        const int c32c = w - 4;
        const int col = c32c * 32 + n32;
#pragma unroll
        for (int kc2 = 0; kc2 < 4; ++kc2) {
          short8 a0 = ldsfrag(sSup + n32 * 68 + kc2 * 16 + kob);
          short8 a1 = ldsfrag(sSup + (32 + n32) * 68 + kc2 * 16 + kob);
          short8 bf = ldsfrag(sPT + col * 68 + kc2 * 16 + kob);
          A0 = __builtin_amdgcn_mfma_f32_32x32x16_bf16(a0, bf, A0, 0, 0, 0);
          A1 = __builtin_amdgcn_mfma_f32_32x32x16_bf16(a1, bf, A1, 0, 0, 0);
        }
        float* curp = Cur + (size_t)(t * BB + b) * NH;
#pragma unroll
        for (int tt = 0; tt < 2; ++tt) {
          const f32x16& ac = tt ? A1 : A0;
#pragma unroll
          for (int g = 0; g < 4; ++g)
#pragma unroll
            for (int i = 0; i < 4; ++i) {
              int row = tt * 32 + 8 * g + 4 * half + i;
              float cv = tanh_fast(ac[4 * g + i] + bcv);
              float uv = uS[row * 128 + col];
              float hold = sHf[row * 128 + col];
              float hn = uv * hold + (1.0f - uv) * cv;
              sHf[row * 128 + col] = hn;
              sHb[row * 132 + col] = f2bf(hn);
              curp[row * 128 + col] = hn;
            }
        }
      } else if (w < 4 || w >= 12) {
        if (t < TT - 1) {  // stage x_{t+1}
          const float* xn = xbase + (size_t)((t + 1) * BB + b) * NH;
          int sidx = (w < 4 ? w : w - 8) * 64 + lane;  // 0..511, 16 elems each
          int r = sidx >> 3, c0 = (sidx & 7) * 16;
          const float* sp = xn + r * 128 + c0;
          unsigned short* dp = sX + r * 132 + c0;
#pragma unroll
          for (int q4 = 0; q4 < 4; ++q4) {
            float4 v = *(const float4*)(sp + q4 * 4);
            *(uint2*)(dp + q4 * 4) = pack4(v.x, v.y, v.z, v.w);
          }
        }
      }
      __syncthreads();  // B4

      // ===== g = h@M (w8-15, one 32x32 tile each), M-frags streamed from L2 =====
      if (w >= 8) {
        const int rt5 = (w - 8) >> 2;    // row tile 0..1
        const int c32q = (w - 8) & 3;    // col tile 0..3
        const unsigned short* qb = Wp + Lw + 196608 + (((c32q * 8) << 9) + lane * 8);
#pragma unroll
        for (int z = 0; z < 16; ++z) A0[z] = 0.0f;
#pragma unroll
        for (int kc = 0; kc < 8; ++kc) {
          short8 a0 = ldsfrag(sHb + (rt5 * 32 + n32) * 132 + kc * 16 + kob);
          short8 bf = ldgfrag(qb + (kc << 9));
          A0 = __builtin_amdgcn_mfma_f32_32x32x16_bf16(a0, bf, A0, 0, 0, 0);
        }
        const int col = c32q * 32 + n32;
#pragma unroll
        for (int g = 0; g < 4; ++g)
#pragma unroll
          for (int i = 0; i < 4; ++i)
            sQ[(rt5 * 32 + 8 * g + 4 * half + i) * 132 + col] = f2bf(A0[4 * g + i]);
      }
      __syncthreads();  // B5

      // ===== scores = g @ h^T, relu (w0-3); B-operand reads sHb directly =====
      if (w < 4) {
        const int rt = w & 1, ct = w >> 1;
#pragma unroll
        for (int z = 0; z < 16; ++z) A0[z] = 0.0f;
#pragma unroll
        for (int kc = 0; kc < 8; ++kc) {
          short8 a0 = ldsfrag(sQ + (rt * 32 + n32) * 132 + kc * 16 + kob);
          short8 bf = ldsfrag(sHb + (ct * 32 + n32) * 132 + kc * 16 + kob);
          A0 = __builtin_amdgcn_mfma_f32_32x32x16_bf16(a0, bf, A0, 0, 0, 0);
        }
#pragma unroll
        for (int g = 0; g < 4; ++g)
#pragma unroll
          for (int i = 0; i < 4; ++i)
            sS[(rt * 32 + 8 * g + 4 * half + i) * 66 + ct * 32 + n32] = fmaxf(A0[4 * g + i], 0.0f);
      }
      __syncthreads();  // B6

      // ===== row softmax -> sSup (all 1024 threads, 16 per row) =====
      {
        int row = tid >> 4, ci = (tid & 15) * 4;
        float2 v01 = *(const float2*)(sS + row * 66 + ci);
        float2 v23 = *(const float2*)(sS + row * 66 + ci + 2);
        float s0 = v01.x, s1 = v01.y, s2 = v23.x, s3 = v23.y;
        float mx = fmaxf(fmaxf(s0, s1), fmaxf(s2, s3));
#pragma unroll
        for (int off = 1; off < 16; off <<= 1) mx = fmaxf(mx, __shfl_xor(mx, off, 16));
        float e0 = __expf(s0 - mx), e1 = __expf(s1 - mx);
        float e2 = __expf(s2 - mx), e3 = __expf(s3 - mx);
        float sum = e0 + e1 + e2 + e3;
#pragma unroll
        for (int off = 1; off < 16; off <<= 1) sum += __shfl_xor(sum, off, 16);
        float inv = 1.0f / sum;
        *(uint2*)(sSup + row * 68 + ci) = pack4(e0 * inv, e1 * inv, e2 * inv, e3 * inv);
      }
      __syncthreads();  // B7
    }  // t

    // ---- write h_last for this layer (sHf is final h) ----
    {
      float* outp = OutH + (size_t)(layer * BB + b) * NH;
      int r = tid >> 4, c0 = (tid & 15) * 8;
      *(float4*)(outp + r * 128 + c0)     = *(const float4*)(sHf + r * 128 + c0);
      *(float4*)(outp + r * 128 + c0 + 4) = *(const float4*)(sHf + r * 128 + c0 + 4);
    }
    __syncthreads();
  }  // layer
}

extern "C" void kernel_launch(void* const* d_in, const int* in_sizes, int n_in,
                              void* d_out, int out_size, void* d_ws, size_t ws_size,
                              hipStream_t stream) {
  const float* Xin  = (const float*)d_in[0];
  const float* H0   = (const float*)d_in[1];
  const float* Sup0 = (const float*)d_in[2];
  const float* Wg0  = (const float*)d_in[3];
  const float* bg0  = (const float*)d_in[4];
  const float* Wc0  = (const float*)d_in[5];
  const float* bc0  = (const float*)d_in[6];
  const float* Wq0  = (const float*)d_in[7];
  const float* Wk0  = (const float*)d_in[8];
  const float* Wg1  = (const float*)d_in[9];
  const float* bg1  = (const float*)d_in[10];
  const float* Wc1  = (const float*)d_in[11];
  const float* bc1  = (const float*)d_in[12];
  const float* Wq1  = (const float*)d_in[13];
  const float* Wk1  = (const float*)d_in[14];
  unsigned short* Wp = (unsigned short*)d_ws;

  hipFuncSetAttribute(reinterpret_cast<const void*>(sglc_main),
                      hipFuncAttributeMaxDynamicSharedMemorySize, LDS_BYTES);

  hipLaunchKernelGGL(sglc_pack, dim3(1792), dim3(256), 0, stream,
                     Wg0, Wc0, Wq0, Wk0, Wg1, Wc1, Wq1, Wk1, Wp);
  hipLaunchKernelGGL(sglc_packM, dim3(128), dim3(256), 0, stream,
                     Wq0, Wk0, Wq1, Wk1, Wp);
  hipLaunchKernelGGL(sglc_main, dim3(BB), dim3(1024), LDS_BYTES, stream,
                     Xin, H0, Sup0, bg0, bc0, bg1, bc1, Wp, (float*)d_out);
}

// Round 5
// 3413.919 us; speedup vs baseline: 1.0561x; 1.0561x over previous
//
#include <hip/hip_runtime.h>

// SGLC encoder on MI355X: T=64, B=32, N=64, DIN=H=128, 2 layers, dynamic supports.
// One workgroup per batch chain (32 blocks x 1024 thr), bf16 MFMA 32x32x16,
// fragment-packed weights streamed from L2, all activations in LDS.
// v2: fp32 h master in LDS (sHf).
// v4: u gate fp32 in LDS; Wq/Wk preload dropped; final-h store hoisted. (3003 us)
// v5: single shared accumulator -> REGRESSED (+17%, extra spill). Reverted.
// v6: v4 structure (separate per-phase accumulators) + M = Wq@Wk^T precompute:
//     scores = h@M@h^T, so P5 halves to one g=h@M GEMM (8 waves x 8 kc),
//     P6 reads sHb directly as B-operand, sK eliminated.
#define TT 64
#define BB 32
#define NN 64
#define HH 128
#define NH 8192

using short8 = __attribute__((ext_vector_type(8))) short;
using f32x16 = __attribute__((ext_vector_type(16))) float;

__device__ __forceinline__ unsigned short f2bf(float f) {
  unsigned int u = __float_as_uint(f);
  u = (u + 0x7FFFu + ((u >> 16) & 1u)) >> 16;
  return (unsigned short)u;
}
__device__ __forceinline__ float sigm(float x) { return 1.0f / (1.0f + __expf(-x)); }
__device__ __forceinline__ float tanh_fast(float x) { return 2.0f / (1.0f + __expf(-2.0f * x)) - 1.0f; }

__device__ __forceinline__ uint2 pack4(float a, float b, float c, float d) {
  uint2 r;
  r.x = (unsigned int)f2bf(a) | ((unsigned int)f2bf(b) << 16);
  r.y = (unsigned int)f2bf(c) | ((unsigned int)f2bf(d) << 16);
  return r;
}
// LDS fragment load: 8 bf16 at 8B-aligned address
__device__ __forceinline__ short8 ldsfrag(const unsigned short* p) {
  union { uint2 u2[2]; short8 s; } f;
  f.u2[0] = *(const uint2*)p;
  f.u2[1] = *(const uint2*)(p + 4);
  return f.s;
}
// Global fragment load: 16B coalesced from fragment-packed weights
__device__ __forceinline__ short8 ldgfrag(const unsigned short* p) {
  union { uint4 u4; short8 s; } f;
  f.u4 = *(const uint4*)p;
  return f.s;
}

// ---- weight packing: fp32 W[k][c] -> bf16 fragment-major blocks of 512 ushorts per (c32,kc):
// packed[((c32*nkc + kc)<<9) + lane*8 + j] = bf16(W[kc*16 + (lane>>5)*8 + j][c32*32 + (lane&31)])
// Regions per layer (ushort offsets): Wg 0 (nkc=32,ncols=256), Wc 131072 (32,128),
//   M=Wq@Wk^T 196608 (nkc=8,ncols=128)  [written by sglc_packM]
__global__ void sglc_pack(const float* __restrict__ Wg0, const float* __restrict__ Wc0,
                          const float* __restrict__ Wq0, const float* __restrict__ Wk0,
                          const float* __restrict__ Wg1, const float* __restrict__ Wc1,
                          const float* __restrict__ Wq1, const float* __restrict__ Wk1,
                          unsigned short* __restrict__ dst) {
  int idx = blockIdx.x * 256 + threadIdx.x;
  if (idx >= 458752) return;
  int layer = idx / 229376;
  int lo = idx - layer * 229376;
  const float* src; int nkc, ncshift, off;
  if (lo < 131072)      { src = layer ? Wg1 : Wg0; nkc = 32; ncshift = 8; off = 0; }
  else if (lo < 196608) { src = layer ? Wc1 : Wc0; nkc = 32; ncshift = 7; off = 131072; }
  else if (lo < 212992) { src = layer ? Wq1 : Wq0; nkc = 8;  ncshift = 7; off = 196608; }
  else                  { src = layer ? Wk1 : Wk0; nkc = 8;  ncshift = 7; off = 212992; }
  int l2 = lo - off;
  int k = l2 >> ncshift;
  int c = l2 & ((1 << ncshift) - 1);
  int c32 = c >> 5, n32 = c & 31;
  int kc = k >> 4, kl = k & 15;
  int half = kl >> 3, j = kl & 7;
  int lane = half * 32 + n32;
  int dstoff = layer * 229376 + off + (((c32 * nkc + kc) << 9) + lane * 8 + j);
  dst[dstoff] = f2bf(src[(size_t)k * (1 << ncshift) + c]);
}

// ---- M = Wq @ Wk^T (fp32 dot over e=0..127), packed as B-fragments at region 196608
//      (overwrites the raw Wq slot; raw Wk slot unused by sglc_main).
// M[d][d'] = sum_e Wq[d][e]*Wk[d'][e];  g = h@M;  scores = g@h^T  (== (hWq)(hWk)^T)
__global__ void sglc_packM(const float* __restrict__ Wq0, const float* __restrict__ Wk0,
                           const float* __restrict__ Wq1, const float* __restrict__ Wk1,
                           unsigned short* __restrict__ dst) {
  int idx = blockIdx.x * 256 + threadIdx.x;  // 32768 total
  int layer = idx >> 14;
  int off = idx & 16383;
  int block = off >> 9;          // c32*8 + kc, 0..31
  int lane = (off >> 3) & 63;
  int j = off & 7;
  int c32 = block >> 3, kc = block & 7;
  int half = lane >> 5, n32 = lane & 31;
  int a = kc * 16 + half * 8 + j;      // M row (d)
  int bcol = c32 * 32 + n32;           // M col (d')
  const float* Q = layer ? Wq1 : Wq0;
  const float* K = layer ? Wk1 : Wk0;
  float s = 0.0f;
#pragma unroll 4
  for (int e = 0; e < 128; e += 4) {
    float4 qa = *(const float4*)(Q + a * 128 + e);
    float4 kb = *(const float4*)(K + bcol * 128 + e);
    s += qa.x * kb.x + qa.y * kb.y + qa.z * kb.z + qa.w * kb.w;
  }
  dst[layer * 229376 + 196608 + (block << 9) + lane * 8 + j] = f2bf(s);
}

// LDS layout (ushort offsets), all bf16 row stride 132 (A-arrays) / 68 (sup, PT):
#define SX_O   0
#define SH_O   8448
#define SRH_O  16896
#define SQ_O   25344
#define SSUP_O 42240
#define SPT_O  46592
#define LDS_USHORTS 64000      // 128000 bytes of bf16 buffers
#define SHF_BYTES 32768        // + 64x128 fp32 h master
#define LDS_BYTES (LDS_USHORTS * 2 + SHF_BYTES)  // 160768 <= 160 KiB

extern "C" __global__ void __launch_bounds__(1024, 4)
sglc_main(const float* __restrict__ Xin, const float* __restrict__ H0,
          const float* __restrict__ Sup0,
          const float* __restrict__ bg0, const float* __restrict__ bc0,
          const float* __restrict__ bg1, const float* __restrict__ bc1,
          const unsigned short* __restrict__ Wp, float* __restrict__ Out) {
  extern __shared__ unsigned short sm[];
  unsigned short* sX   = sm + SX_O;
  unsigned short* sHb  = sm + SH_O;
  unsigned short* sRH  = sm + SRH_O;
  unsigned short* sQ   = sm + SQ_O;
  unsigned short* sSup = sm + SSUP_O;
  unsigned short* sPT  = sm + SPT_O;
  float* sS  = (float*)(sm + SPT_O);        // overlays sPT (disjoint in time within a step)
  float* uS  = (float*)(sm + SQ_O);         // fp32 u gate, overlays sQ region (free P2->P4), 32 KB
  float* sHf = (float*)(sm + LDS_USHORTS);  // fp32 h master, stride 128 (bank = n32, conflict-free)

  const int b = blockIdx.x;
  const int tid = threadIdx.x;
  const int lane = tid & 63;
  const int w = tid >> 6;
  const int n32 = lane & 31;
  const int half = lane >> 5;
  const int kob = half * 8;

  float* OutH = Out;
  float* Cur  = Out + 2 * BB * NH;

  for (int layer = 0; layer < 2; ++layer) {
    const int Lw = layer * 229376;
    const float* bg = layer ? bg1 : bg0;
    const float* bc = layer ? bc1 : bc0;
    const float* xbase = layer ? Cur : Xin;
    const float* h0p = H0 + (size_t)(layer * BB + b) * NH;

    const float bgv = (w < 8) ? bg[(w & 7) * 32 + n32] : 0.0f;
    const float bcv = (w >= 4 && w < 8) ? bc[(w - 4) * 32 + n32] : 0.0f;

    // ---- layer init: stage h0 (bf16 + fp32 master), sup (layer 0), x_0 ----
    {
      int r = tid >> 4, c0 = (tid & 15) * 8;
      const float* hp = h0p + r * 128 + c0;
      float4 v0 = *(const float4*)(hp);
      float4 v1 = *(const float4*)(hp + 4);
      *(uint2*)(sHb + r * 132 + c0)     = pack4(v0.x, v0.y, v0.z, v0.w);
      *(uint2*)(sHb + r * 132 + c0 + 4) = pack4(v1.x, v1.y, v1.z, v1.w);
      *(float4*)(sHf + r * 128 + c0)     = v0;
      *(float4*)(sHf + r * 128 + c0 + 4) = v1;
      const float* xp = xbase + (size_t)(0 * BB + b) * NH + r * 128 + c0;
      float4 x0 = *(const float4*)(xp);
      float4 x1 = *(const float4*)(xp + 4);
      *(uint2*)(sX + r * 132 + c0)     = pack4(x0.x, x0.y, x0.z, x0.w);
      *(uint2*)(sX + r * 132 + c0 + 4) = pack4(x1.x, x1.y, x1.z, x1.w);
      if (layer == 0) {
        int rs = tid >> 4, cs = (tid & 15) * 4;
        float4 sv = *(const float4*)(Sup0 + (size_t)b * 4096 + rs * 64 + cs);
        *(uint2*)(sSup + rs * 68 + cs) = pack4(sv.x, sv.y, sv.z, sv.w);
      }
    }
    __syncthreads();

    for (int t = 0; t < TT; ++t) {
      f32x16 acc0, acc1;
#pragma unroll
      for (int z = 0; z < 16; ++z) { acc0[z] = 0.0f; acc1[z] = 0.0f; }

      // ===== gates GEMM: P1 = xh@Wg[0:256,:] (w0-7), P2 = xh@Wg[256:512,:] (w8-15) =====
      {
        const int c32g = w & 7;
        const unsigned short* wb = Wp + Lw + (((c32g * 32 + (w < 8 ? 0 : 16)) << 9) + lane * 8);
#pragma unroll
        for (int kc = 0; kc < 16; ++kc) {
          const unsigned short* asrc = (kc < 8) ? (sX + kc * 16 + kob) : (sHb + (kc - 8) * 16 + kob);
          short8 a0 = ldsfrag(asrc + n32 * 132);
          short8 a1 = ldsfrag(asrc + (32 + n32) * 132);
          short8 bf = ldgfrag(wb + (kc << 9));
          acc0 = __builtin_amdgcn_mfma_f32_32x32x16_bf16(a0, bf, acc0, 0, 0, 0);
          acc1 = __builtin_amdgcn_mfma_f32_32x32x16_bf16(a1, bf, acc1, 0, 0, 0);
        }
        if (w >= 8) {  // write P2^T (bf16) for the conv
          unsigned short* pb = sPT + (c32g * 32 + n32) * 68;
#pragma unroll
          for (int tt = 0; tt < 2; ++tt) {
            const f32x16& ac = tt ? acc1 : acc0;
#pragma unroll
            for (int g = 0; g < 4; ++g)
              *(uint2*)(pb + tt * 32 + 8 * g + 4 * half) =
                  pack4(ac[4 * g], ac[4 * g + 1], ac[4 * g + 2], ac[4 * g + 3]);
          }
        }
      }
      __syncthreads();  // B1

      // ===== conv r/u (w0-7): acc += sup @ P2 =====
      if (w < 8) {
        const int c32g = w & 7;
#pragma unroll
        for (int kc2 = 0; kc2 < 4; ++kc2) {
          short8 a0 = ldsfrag(sSup + n32 * 68 + kc2 * 16 + kob);
          short8 a1 = ldsfrag(sSup + (32 + n32) * 68 + kc2 * 16 + kob);
          short8 bf = ldsfrag(sPT + (c32g * 32 + n32) * 68 + kc2 * 16 + kob);
          acc0 = __builtin_amdgcn_mfma_f32_32x32x16_bf16(a0, bf, acc0, 0, 0, 0);
          acc1 = __builtin_amdgcn_mfma_f32_32x32x16_bf16(a1, bf, acc1, 0, 0, 0);
        }
        if (w < 4) {  // r -> rh into sRH (bf16), h from fp32 master
          const int col = (w & 7) * 32 + n32;
#pragma unroll
          for (int tt = 0; tt < 2; ++tt) {
            const f32x16& ac = tt ? acc1 : acc0;
#pragma unroll
            for (int g = 0; g < 4; ++g)
#pragma unroll
              for (int i = 0; i < 4; ++i) {
                int row = tt * 32 + 8 * g + 4 * half + i;
                float rv = sigm(ac[4 * g + i] + bgv);
                float hv = sHf[row * 128 + col];
                sRH[row * 132 + col] = f2bf(rv * hv);
              }
          }
        } else {  // u -> fp32 LDS (sQ region, free until P5)
          const int ucol = (w - 4) * 32 + n32;
#pragma unroll
          for (int tt = 0; tt < 2; ++tt) {
            const f32x16& ac = tt ? acc1 : acc0;
#pragma unroll
            for (int g = 0; g < 4; ++g)
#pragma unroll
              for (int i = 0; i < 4; ++i) {
                int row = tt * 32 + 8 * g + 4 * half + i;
                uS[row * 128 + ucol] = sigm(ac[4 * g + i] + bgv);
              }
          }
        }
      }
      __syncthreads();  // B2

      // ===== candidate GEMM: Q1 = xh_r@Wc[0:256] (w4-7), Q2 = xh_r@Wc[256:512] (w8-11) =====
      f32x16 ca0, ca1;
#pragma unroll
      for (int z = 0; z < 16; ++z) { ca0[z] = 0.0f; ca1[z] = 0.0f; }
      if (w >= 4 && w < 12) {
        const int c32c = (w < 8) ? (w - 4) : (w - 8);
        const unsigned short* wb = Wp + Lw + 131072 + (((c32c * 32 + (w < 8 ? 0 : 16)) << 9) + lane * 8);
#pragma unroll
        for (int kc = 0; kc < 16; ++kc) {
          const unsigned short* asrc = (kc < 8) ? (sX + kc * 16 + kob) : (sRH + (kc - 8) * 16 + kob);
          short8 a0 = ldsfrag(asrc + n32 * 132);
          short8 a1 = ldsfrag(asrc + (32 + n32) * 132);
          short8 bf = ldgfrag(wb + (kc << 9));
          ca0 = __builtin_amdgcn_mfma_f32_32x32x16_bf16(a0, bf, ca0, 0, 0, 0);
          ca1 = __builtin_amdgcn_mfma_f32_32x32x16_bf16(a1, bf, ca1, 0, 0, 0);
        }
        if (w >= 8) {  // write Q2^T
          unsigned short* pb = sPT + (c32c * 32 + n32) * 68;
#pragma unroll
          for (int tt = 0; tt < 2; ++tt) {
            const f32x16& ac = tt ? ca1 : ca0;
#pragma unroll
            for (int g = 0; g < 4; ++g)
              *(uint2*)(pb + tt * 32 + 8 * g + 4 * half) =
                  pack4(ac[4 * g], ac[4 * g + 1], ac[4 * g + 2], ac[4 * g + 3]);
          }
        }
      }
      __syncthreads();  // B3

      // ===== conv c + h update (w4-7); x_{t+1} staging (w0-3, w12-15) =====
      if (w >= 4 && w < 8) {
        const int c32c = w - 4;
        const int col = c32c * 32 + n32;
#pragma unroll
        for (int kc2 = 0; kc2 < 4; ++kc2) {
          short8 a0 = ldsfrag(sSup + n32 * 68 + kc2 * 16 + kob);
          short8 a1 = ldsfrag(sSup + (32 + n32) * 68 + kc2 * 16 + kob);
          short8 bf = ldsfrag(sPT + col * 68 + kc2 * 16 + kob);
          ca0 = __builtin_amdgcn_mfma_f32_32x32x16_bf16(a0, bf, ca0, 0, 0, 0);
          ca1 = __builtin_amdgcn_mfma_f32_32x32x16_bf16(a1, bf, ca1, 0, 0, 0);
        }
        float* curp = Cur + (size_t)(t * BB + b) * NH;
#pragma unroll
        for (int tt = 0; tt < 2; ++tt) {
          const f32x16& ac = tt ? ca1 : ca0;
#pragma unroll
          for (int g = 0; g < 4; ++g)
#pragma unroll
            for (int i = 0; i < 4; ++i) {
              int row = tt * 32 + 8 * g + 4 * half + i;
              float cv = tanh_fast(ac[4 * g + i] + bcv);
              float uv = uS[row * 128 + col];
              float hold = sHf[row * 128 + col];
              float hn = uv * hold + (1.0f - uv) * cv;
              sHf[row * 128 + col] = hn;
              sHb[row * 132 + col] = f2bf(hn);
              curp[row * 128 + col] = hn;
            }
        }
      } else if (w < 4 || w >= 12) {
        if (t < TT - 1) {  // stage x_{t+1}
          const float* xn = xbase + (size_t)((t + 1) * BB + b) * NH;
          int sidx = (w < 4 ? w : w - 8) * 64 + lane;  // 0..511, 16 elems each
          int r = sidx >> 3, c0 = (sidx & 7) * 16;
          const float* sp = xn + r * 128 + c0;
          unsigned short* dp = sX + r * 132 + c0;
#pragma unroll
          for (int q4 = 0; q4 < 4; ++q4) {
            float4 v = *(const float4*)(sp + q4 * 4);
            *(uint2*)(dp + q4 * 4) = pack4(v.x, v.y, v.z, v.w);
          }
        }
      }
      __syncthreads();  // B4

      // ===== g = h@M (w8-15, one 32x32 tile each), M-frags streamed from L2 =====
      if (w >= 8) {
        const int rt5 = (w - 8) >> 2;    // row tile 0..1
        const int c32q = (w - 8) & 3;    // col tile 0..3
        const unsigned short* qb = Wp + Lw + 196608 + (((c32q * 8) << 9) + lane * 8);
        f32x16 qa0;
#pragma unroll
        for (int z = 0; z < 16; ++z) qa0[z] = 0.0f;
#pragma unroll
        for (int kc = 0; kc < 8; ++kc) {
          short8 a0 = ldsfrag(sHb + (rt5 * 32 + n32) * 132 + kc * 16 + kob);
          short8 bf = ldgfrag(qb + (kc << 9));
          qa0 = __builtin_amdgcn_mfma_f32_32x32x16_bf16(a0, bf, qa0, 0, 0, 0);
        }
        const int col = c32q * 32 + n32;
#pragma unroll
        for (int g = 0; g < 4; ++g)
#pragma unroll
          for (int i = 0; i < 4; ++i)
            sQ[(rt5 * 32 + 8 * g + 4 * half + i) * 132 + col] = f2bf(qa0[4 * g + i]);
      }
      __syncthreads();  // B5

      // ===== scores = g @ h^T, relu (w0-3); B-operand reads sHb directly =====
      if (w < 4) {
        const int rt = w & 1, ct = w >> 1;
        f32x16 sa;
#pragma unroll
        for (int z = 0; z < 16; ++z) sa[z] = 0.0f;
#pragma unroll
        for (int kc = 0; kc < 8; ++kc) {
          short8 a0 = ldsfrag(sQ + (rt * 32 + n32) * 132 + kc * 16 + kob);
          short8 bf = ldsfrag(sHb + (ct * 32 + n32) * 132 + kc * 16 + kob);
          sa = __builtin_amdgcn_mfma_f32_32x32x16_bf16(a0, bf, sa, 0, 0, 0);
        }
#pragma unroll
        for (int g = 0; g < 4; ++g)
#pragma unroll
          for (int i = 0; i < 4; ++i)
            sS[(rt * 32 + 8 * g + 4 * half + i) * 66 + ct * 32 + n32] = fmaxf(sa[4 * g + i], 0.0f);
      }
      __syncthreads();  // B6

      // ===== row softmax -> sSup (all 1024 threads, 16 per row) =====
      {
        int row = tid >> 4, ci = (tid & 15) * 4;
        float2 v01 = *(const float2*)(sS + row * 66 + ci);
        float2 v23 = *(const float2*)(sS + row * 66 + ci + 2);
        float s0 = v01.x, s1 = v01.y, s2 = v23.x, s3 = v23.y;
        float mx = fmaxf(fmaxf(s0, s1), fmaxf(s2, s3));
#pragma unroll
        for (int off = 1; off < 16; off <<= 1) mx = fmaxf(mx, __shfl_xor(mx, off, 16));
        float e0 = __expf(s0 - mx), e1 = __expf(s1 - mx);
        float e2 = __expf(s2 - mx), e3 = __expf(s3 - mx);
        float sum = e0 + e1 + e2 + e3;
#pragma unroll
        for (int off = 1; off < 16; off <<= 1) sum += __shfl_xor(sum, off, 16);
        float inv = 1.0f / sum;
        *(uint2*)(sSup + row * 68 + ci) = pack4(e0 * inv, e1 * inv, e2 * inv, e3 * inv);
      }
      __syncthreads();  // B7
    }  // t

    // ---- write h_last for this layer (sHf is final h) ----
    {
      float* outp = OutH + (size_t)(layer * BB + b) * NH;
      int r = tid >> 4, c0 = (tid & 15) * 8;
      *(float4*)(outp + r * 128 + c0)     = *(const float4*)(sHf + r * 128 + c0);
      *(float4*)(outp + r * 128 + c0 + 4) = *(const float4*)(sHf + r * 128 + c0 + 4);
    }
    __syncthreads();
  }  // layer
}

extern "C" void kernel_launch(void* const* d_in, const int* in_sizes, int n_in,
                              void* d_out, int out_size, void* d_ws, size_t ws_size,
                              hipStream_t stream) {
  const float* Xin  = (const float*)d_in[0];
  const float* H0   = (const float*)d_in[1];
  const float* Sup0 = (const float*)d_in[2];
  const float* Wg0  = (const float*)d_in[3];
  const float* bg0  = (const float*)d_in[4];
  const float* Wc0  = (const float*)d_in[5];
  const float* bc0  = (const float*)d_in[6];
  const float* Wq0  = (const float*)d_in[7];
  const float* Wk0  = (const float*)d_in[8];
  const float* Wg1  = (const float*)d_in[9];
  const float* bg1  = (const float*)d_in[10];
  const float* Wc1  = (const float*)d_in[11];
  const float* bc1  = (const float*)d_in[12];
  const float* Wq1  = (const float*)d_in[13];
  const float* Wk1  = (const float*)d_in[14];
  unsigned short* Wp = (unsigned short*)d_ws;

  hipFuncSetAttribute(reinterpret_cast<const void*>(sglc_main),
                      hipFuncAttributeMaxDynamicSharedMemorySize, LDS_BYTES);

  hipLaunchKernelGGL(sglc_pack, dim3(1792), dim3(256), 0, stream,
                     Wg0, Wc0, Wq0, Wk0, Wg1, Wc1, Wq1, Wk1, Wp);
  hipLaunchKernelGGL(sglc_packM, dim3(128), dim3(256), 0, stream,
                     Wq0, Wk0, Wq1, Wk1, Wp);
  hipLaunchKernelGGL(sglc_main, dim3(BB), dim3(1024), LDS_BYTES, stream,
                     Xin, H0, Sup0, bg0, bc0, bg1, bc1, Wp, (float*)d_out);
}

// Round 6
// 3038.620 us; speedup vs baseline: 1.1865x; 1.1235x over previous
//
#include <hip/hip_runtime.h>

// SGLC encoder on MI355X: T=64, B=32, N=64, DIN=H=128, 2 layers, dynamic supports.
// One workgroup per batch chain (32 blocks x 1024 thr), bf16 MFMA 32x32x16,
// fragment-packed weights streamed from L2, all activations in LDS.
// v2: fp32 h master in LDS (sHf).
// v4: u gate fp32 in LDS; Wq/Wk preload dropped; final-h store hoisted. (3003 us)
// v5: single shared accumulator -> REGRESSED (+17%). Reverted.
// v6: M=Wq@Wk^T precompute -> REGRESSED (+10%). Reverted.
// v7: v4 EXACTLY + 4-deep rotating register prefetch of the L2 weight-fragment
//     streams in P1/P3/P5 (explicit software pipeline; load kc+4 issues before
//     MFMA kc). No layout/algorithm/numerics change.
#define TT 64
#define BB 32
#define NN 64
#define HH 128
#define NH 8192

using short8 = __attribute__((ext_vector_type(8))) short;
using f32x16 = __attribute__((ext_vector_type(16))) float;

__device__ __forceinline__ unsigned short f2bf(float f) {
  unsigned int u = __float_as_uint(f);
  u = (u + 0x7FFFu + ((u >> 16) & 1u)) >> 16;
  return (unsigned short)u;
}
__device__ __forceinline__ float bf2f(unsigned short s) {
  return __uint_as_float(((unsigned int)s) << 16);
}
__device__ __forceinline__ float sigm(float x) { return 1.0f / (1.0f + __expf(-x)); }
__device__ __forceinline__ float tanh_fast(float x) { return 2.0f / (1.0f + __expf(-2.0f * x)) - 1.0f; }

__device__ __forceinline__ uint2 pack4(float a, float b, float c, float d) {
  uint2 r;
  r.x = (unsigned int)f2bf(a) | ((unsigned int)f2bf(b) << 16);
  r.y = (unsigned int)f2bf(c) | ((unsigned int)f2bf(d) << 16);
  return r;
}
// LDS fragment load: 8 bf16 at 8B-aligned address
__device__ __forceinline__ short8 ldsfrag(const unsigned short* p) {
  union { uint2 u2[2]; short8 s; } f;
  f.u2[0] = *(const uint2*)p;
  f.u2[1] = *(const uint2*)(p + 4);
  return f.s;
}
// Global fragment load: 16B coalesced from fragment-packed weights
__device__ __forceinline__ short8 ldgfrag(const unsigned short* p) {
  union { uint4 u4; short8 s; } f;
  f.u4 = *(const uint4*)p;
  return f.s;
}

// ---- weight packing: fp32 W[k][c] -> bf16 fragment-major blocks of 512 ushorts per (c32,kc):
// packed[((c32*nkc + kc)<<9) + lane*8 + j] = bf16(W[kc*16 + (lane>>5)*8 + j][c32*32 + (lane&31)])
// Regions per layer (ushort offsets): Wg 0 (nkc=32,ncols=256), Wc 131072 (32,128), Wq 196608 (8,128), Wk 212992 (8,128)
__global__ void sglc_pack(const float* __restrict__ Wg0, const float* __restrict__ Wc0,
                          const float* __restrict__ Wq0, const float* __restrict__ Wk0,
                          const float* __restrict__ Wg1, const float* __restrict__ Wc1,
                          const float* __restrict__ Wq1, const float* __restrict__ Wk1,
                          unsigned short* __restrict__ dst) {
  int idx = blockIdx.x * 256 + threadIdx.x;
  if (idx >= 458752) return;
  int layer = idx / 229376;
  int lo = idx - layer * 229376;
  const float* src; int nkc, ncshift, off;
  if (lo < 131072)      { src = layer ? Wg1 : Wg0; nkc = 32; ncshift = 8; off = 0; }
  else if (lo < 196608) { src = layer ? Wc1 : Wc0; nkc = 32; ncshift = 7; off = 131072; }
  else if (lo < 212992) { src = layer ? Wq1 : Wq0; nkc = 8;  ncshift = 7; off = 196608; }
  else                  { src = layer ? Wk1 : Wk0; nkc = 8;  ncshift = 7; off = 212992; }
  int l2 = lo - off;
  int k = l2 >> ncshift;
  int c = l2 & ((1 << ncshift) - 1);
  int c32 = c >> 5, n32 = c & 31;
  int kc = k >> 4, kl = k & 15;
  int half = kl >> 3, j = kl & 7;
  int lane = half * 32 + n32;
  int dstoff = layer * 229376 + off + (((c32 * nkc + kc) << 9) + lane * 8 + j);
  dst[dstoff] = f2bf(src[(size_t)k * (1 << ncshift) + c]);
}

// LDS layout (ushort offsets), all bf16 row stride 132 (A-arrays) / 68 (sup, PT):
#define SX_O   0
#define SH_O   8448
#define SRH_O  16896
#define SQ_O   25344
#define SK_O   33792
#define SSUP_O 42240
#define SPT_O  46592
#define LDS_USHORTS 64000      // 128000 bytes of bf16 buffers
#define SHF_BYTES 32768        // + 64x128 fp32 h master
#define LDS_BYTES (LDS_USHORTS * 2 + SHF_BYTES)  // 160768 <= 160 KiB

extern "C" __global__ void __launch_bounds__(1024, 4)
sglc_main(const float* __restrict__ Xin, const float* __restrict__ H0,
          const float* __restrict__ Sup0,
          const float* __restrict__ bg0, const float* __restrict__ bc0,
          const float* __restrict__ bg1, const float* __restrict__ bc1,
          const unsigned short* __restrict__ Wp, float* __restrict__ Out) {
  extern __shared__ unsigned short sm[];
  unsigned short* sX   = sm + SX_O;
  unsigned short* sHb  = sm + SH_O;
  unsigned short* sRH  = sm + SRH_O;
  unsigned short* sQ   = sm + SQ_O;
  unsigned short* sK   = sm + SK_O;
  unsigned short* sSup = sm + SSUP_O;
  unsigned short* sPT  = sm + SPT_O;
  float* sS  = (float*)(sm + SPT_O);        // overlays sPT (disjoint in time within a step)
  float* uS  = (float*)(sm + SQ_O);         // fp32 u gate, overlays sQ/sK (free P2->P5), 32 KB
  float* sHf = (float*)(sm + LDS_USHORTS);  // fp32 h master, stride 128 (bank = n32, conflict-free)

  const int b = blockIdx.x;
  const int tid = threadIdx.x;
  const int lane = tid & 63;
  const int w = tid >> 6;
  const int n32 = lane & 31;
  const int half = lane >> 5;
  const int kob = half * 8;

  float* OutH = Out;
  float* Cur  = Out + 2 * BB * NH;

  for (int layer = 0; layer < 2; ++layer) {
    const int Lw = layer * 229376;
    const float* bg = layer ? bg1 : bg0;
    const float* bc = layer ? bc1 : bc0;
    const float* xbase = layer ? Cur : Xin;
    const float* h0p = H0 + (size_t)(layer * BB + b) * NH;

    const float bgv = (w < 8) ? bg[(w & 7) * 32 + n32] : 0.0f;
    const float bcv = (w >= 4 && w < 8) ? bc[(w - 4) * 32 + n32] : 0.0f;

    // ---- layer init: stage h0 (bf16 + fp32 master), sup (layer 0), x_0 ----
    {
      int r = tid >> 4, c0 = (tid & 15) * 8;
      const float* hp = h0p + r * 128 + c0;
      float4 v0 = *(const float4*)(hp);
      float4 v1 = *(const float4*)(hp + 4);
      *(uint2*)(sHb + r * 132 + c0)     = pack4(v0.x, v0.y, v0.z, v0.w);
      *(uint2*)(sHb + r * 132 + c0 + 4) = pack4(v1.x, v1.y, v1.z, v1.w);
      *(float4*)(sHf + r * 128 + c0)     = v0;
      *(float4*)(sHf + r * 128 + c0 + 4) = v1;
      const float* xp = xbase + (size_t)(0 * BB + b) * NH + r * 128 + c0;
      float4 x0 = *(const float4*)(xp);
      float4 x1 = *(const float4*)(xp + 4);
      *(uint2*)(sX + r * 132 + c0)     = pack4(x0.x, x0.y, x0.z, x0.w);
      *(uint2*)(sX + r * 132 + c0 + 4) = pack4(x1.x, x1.y, x1.z, x1.w);
      if (layer == 0) {
        int rs = tid >> 4, cs = (tid & 15) * 4;
        float4 sv = *(const float4*)(Sup0 + (size_t)b * 4096 + rs * 64 + cs);
        *(uint2*)(sSup + rs * 68 + cs) = pack4(sv.x, sv.y, sv.z, sv.w);
      }
    }
    __syncthreads();

    for (int t = 0; t < TT; ++t) {
      f32x16 acc0, acc1;
#pragma unroll
      for (int z = 0; z < 16; ++z) { acc0[z] = 0.0f; acc1[z] = 0.0f; }

      // ===== gates GEMM: P1 = xh@Wg[0:256,:] (w0-7), P2 = xh@Wg[256:512,:] (w8-15) =====
      {
        const int c32g = w & 7;
        const unsigned short* wb = Wp + Lw + (((c32g * 32 + (w < 8 ? 0 : 16)) << 9) + lane * 8);
        short8 wf[4];  // 4-deep rotating weight prefetch (static indices after unroll)
#pragma unroll
        for (int i = 0; i < 4; ++i) wf[i] = ldgfrag(wb + (i << 9));
#pragma unroll
        for (int kc = 0; kc < 16; ++kc) {
          short8 bf = wf[kc & 3];
          if (kc + 4 < 16) wf[kc & 3] = ldgfrag(wb + ((kc + 4) << 9));
          const unsigned short* asrc = (kc < 8) ? (sX + kc * 16 + kob) : (sHb + (kc - 8) * 16 + kob);
          short8 a0 = ldsfrag(asrc + n32 * 132);
          short8 a1 = ldsfrag(asrc + (32 + n32) * 132);
          acc0 = __builtin_amdgcn_mfma_f32_32x32x16_bf16(a0, bf, acc0, 0, 0, 0);
          acc1 = __builtin_amdgcn_mfma_f32_32x32x16_bf16(a1, bf, acc1, 0, 0, 0);
        }
        if (w >= 8) {  // write P2^T (bf16) for the conv
          unsigned short* pb = sPT + (c32g * 32 + n32) * 68;
#pragma unroll
          for (int tt = 0; tt < 2; ++tt) {
            const f32x16& ac = tt ? acc1 : acc0;
#pragma unroll
            for (int g = 0; g < 4; ++g)
              *(uint2*)(pb + tt * 32 + 8 * g + 4 * half) =
                  pack4(ac[4 * g], ac[4 * g + 1], ac[4 * g + 2], ac[4 * g + 3]);
          }
        }
      }
      __syncthreads();  // B1

      // ===== conv r/u (w0-7): acc += sup @ P2 =====
      if (w < 8) {
        const int c32g = w & 7;
#pragma unroll
        for (int kc2 = 0; kc2 < 4; ++kc2) {
          short8 a0 = ldsfrag(sSup + n32 * 68 + kc2 * 16 + kob);
          short8 a1 = ldsfrag(sSup + (32 + n32) * 68 + kc2 * 16 + kob);
          short8 bf = ldsfrag(sPT + (c32g * 32 + n32) * 68 + kc2 * 16 + kob);
          acc0 = __builtin_amdgcn_mfma_f32_32x32x16_bf16(a0, bf, acc0, 0, 0, 0);
          acc1 = __builtin_amdgcn_mfma_f32_32x32x16_bf16(a1, bf, acc1, 0, 0, 0);
        }
        if (w < 4) {  // r -> rh into sRH (bf16)
          const int col = (w & 7) * 32 + n32;
#pragma unroll
          for (int tt = 0; tt < 2; ++tt) {
            const f32x16& ac = tt ? acc1 : acc0;
#pragma unroll
            for (int g = 0; g < 4; ++g)
#pragma unroll
              for (int i = 0; i < 4; ++i) {
                int row = tt * 32 + 8 * g + 4 * half + i;
                float rv = sigm(ac[4 * g + i] + bgv);
                float hv = bf2f(sHb[row * 132 + col]);
                sRH[row * 132 + col] = f2bf(rv * hv);
              }
          }
        } else {  // u -> fp32 LDS (sQ/sK region, free until P5)
          const int ucol = (w - 4) * 32 + n32;
#pragma unroll
          for (int tt = 0; tt < 2; ++tt) {
            const f32x16& ac = tt ? acc1 : acc0;
#pragma unroll
            for (int g = 0; g < 4; ++g)
#pragma unroll
              for (int i = 0; i < 4; ++i) {
                int row = tt * 32 + 8 * g + 4 * half + i;
                uS[row * 128 + ucol] = sigm(ac[4 * g + i] + bgv);
              }
          }
        }
      }
      __syncthreads();  // B2

      // ===== candidate GEMM: Q1 = xh_r@Wc[0:256] (w4-7), Q2 = xh_r@Wc[256:512] (w8-11) =====
      f32x16 ca0, ca1;
#pragma unroll
      for (int z = 0; z < 16; ++z) { ca0[z] = 0.0f; ca1[z] = 0.0f; }
      if (w >= 4 && w < 12) {
        const int c32c = (w < 8) ? (w - 4) : (w - 8);
        const unsigned short* wb = Wp + Lw + 131072 + (((c32c * 32 + (w < 8 ? 0 : 16)) << 9) + lane * 8);
        short8 wf[4];
#pragma unroll
        for (int i = 0; i < 4; ++i) wf[i] = ldgfrag(wb + (i << 9));
#pragma unroll
        for (int kc = 0; kc < 16; ++kc) {
          short8 bf = wf[kc & 3];
          if (kc + 4 < 16) wf[kc & 3] = ldgfrag(wb + ((kc + 4) << 9));
          const unsigned short* asrc = (kc < 8) ? (sX + kc * 16 + kob) : (sRH + (kc - 8) * 16 + kob);
          short8 a0 = ldsfrag(asrc + n32 * 132);
          short8 a1 = ldsfrag(asrc + (32 + n32) * 132);
          ca0 = __builtin_amdgcn_mfma_f32_32x32x16_bf16(a0, bf, ca0, 0, 0, 0);
          ca1 = __builtin_amdgcn_mfma_f32_32x32x16_bf16(a1, bf, ca1, 0, 0, 0);
        }
        if (w >= 8) {  // write Q2^T
          unsigned short* pb = sPT + (c32c * 32 + n32) * 68;
#pragma unroll
          for (int tt = 0; tt < 2; ++tt) {
            const f32x16& ac = tt ? ca1 : ca0;
#pragma unroll
            for (int g = 0; g < 4; ++g)
              *(uint2*)(pb + tt * 32 + 8 * g + 4 * half) =
                  pack4(ac[4 * g], ac[4 * g + 1], ac[4 * g + 2], ac[4 * g + 3]);
          }
        }
      }
      __syncthreads();  // B3

      // ===== conv c + h update (w4-7); x_{t+1} staging (w0-3, w12-15) =====
      if (w >= 4 && w < 8) {
        const int c32c = w - 4;
        const int col = c32c * 32 + n32;
#pragma unroll
        for (int kc2 = 0; kc2 < 4; ++kc2) {
          short8 a0 = ldsfrag(sSup + n32 * 68 + kc2 * 16 + kob);
          short8 a1 = ldsfrag(sSup + (32 + n32) * 68 + kc2 * 16 + kob);
          short8 bf = ldsfrag(sPT + col * 68 + kc2 * 16 + kob);
          ca0 = __builtin_amdgcn_mfma_f32_32x32x16_bf16(a0, bf, ca0, 0, 0, 0);
          ca1 = __builtin_amdgcn_mfma_f32_32x32x16_bf16(a1, bf, ca1, 0, 0, 0);
        }
        float* curp = Cur + (size_t)(t * BB + b) * NH;
#pragma unroll
        for (int tt = 0; tt < 2; ++tt) {
          const f32x16& ac = tt ? ca1 : ca0;
#pragma unroll
          for (int g = 0; g < 4; ++g)
#pragma unroll
            for (int i = 0; i < 4; ++i) {
              int row = tt * 32 + 8 * g + 4 * half + i;
              float cv = tanh_fast(ac[4 * g + i] + bcv);
              float uv = uS[row * 128 + col];
              float hold = sHf[row * 128 + col];
              float hn = uv * hold + (1.0f - uv) * cv;
              sHf[row * 128 + col] = hn;
              sHb[row * 132 + col] = f2bf(hn);
              curp[row * 128 + col] = hn;
            }
        }
      } else if (w < 4 || w >= 12) {
        if (t < TT - 1) {  // stage x_{t+1}
          const float* xn = xbase + (size_t)((t + 1) * BB + b) * NH;
          int sidx = (w < 4 ? w : w - 8) * 64 + lane;  // 0..511, 16 elems each
          int r = sidx >> 3, c0 = (sidx & 7) * 16;
          const float* sp = xn + r * 128 + c0;
          unsigned short* dp = sX + r * 132 + c0;
#pragma unroll
          for (int q4 = 0; q4 < 4; ++q4) {
            float4 v = *(const float4*)(sp + q4 * 4);
            *(uint2*)(dp + q4 * 4) = pack4(v.x, v.y, v.z, v.w);
          }
        }
      }
      __syncthreads();  // B4

      // ===== q = h@Wq (w8-11), k = h@Wk (w12-15), B-frags streamed from L2 =====
      if (w >= 8) {
        const unsigned short* qb =
            Wp + Lw + ((w < 12) ? 196608 : 212992) + ((((w - 8) & 3) * 8) << 9) + lane * 8;
        const int col = ((w - 8) & 3) * 32 + n32;
        f32x16 qa0, qa1;
#pragma unroll
        for (int z = 0; z < 16; ++z) { qa0[z] = 0.0f; qa1[z] = 0.0f; }
        short8 wf[4];
#pragma unroll
        for (int i = 0; i < 4; ++i) wf[i] = ldgfrag(qb + (i << 9));
#pragma unroll
        for (int kc = 0; kc < 8; ++kc) {
          short8 bf = wf[kc & 3];
          if (kc + 4 < 8) wf[kc & 3] = ldgfrag(qb + ((kc + 4) << 9));
          short8 a0 = ldsfrag(sHb + n32 * 132 + kc * 16 + kob);
          short8 a1 = ldsfrag(sHb + (32 + n32) * 132 + kc * 16 + kob);
          qa0 = __builtin_amdgcn_mfma_f32_32x32x16_bf16(a0, bf, qa0, 0, 0, 0);
          qa1 = __builtin_amdgcn_mfma_f32_32x32x16_bf16(a1, bf, qa1, 0, 0, 0);
        }
        unsigned short* dstm = (w < 12) ? sQ : sK;
#pragma unroll
        for (int tt = 0; tt < 2; ++tt) {
          const f32x16& ac = tt ? qa1 : qa0;
#pragma unroll
          for (int g = 0; g < 4; ++g)
#pragma unroll
            for (int i = 0; i < 4; ++i)
              dstm[(tt * 32 + 8 * g + 4 * half + i) * 132 + col] = f2bf(ac[4 * g + i]);
        }
      }
      __syncthreads();  // B5

      // ===== scores = q @ k^T, relu (w0-3) =====
      if (w < 4) {
        const int rt = w & 1, ct = w >> 1;
        f32x16 sa;
#pragma unroll
        for (int z = 0; z < 16; ++z) sa[z] = 0.0f;
#pragma unroll
        for (int kc = 0; kc < 8; ++kc) {
          short8 a0 = ldsfrag(sQ + (rt * 32 + n32) * 132 + kc * 16 + kob);
          short8 bf = ldsfrag(sK + (ct * 32 + n32) * 132 + kc * 16 + kob);
          sa = __builtin_amdgcn_mfma_f32_32x32x16_bf16(a0, bf, sa, 0, 0, 0);
        }
#pragma unroll
        for (int g = 0; g < 4; ++g)
#pragma unroll
          for (int i = 0; i < 4; ++i)
            sS[(rt * 32 + 8 * g + 4 * half + i) * 66 + ct * 32 + n32] = fmaxf(sa[4 * g + i], 0.0f);
      }
      __syncthreads();  // B6

      // ===== row softmax -> sSup (all 1024 threads, 16 per row) =====
      {
        int row = tid >> 4, ci = (tid & 15) * 4;
        float2 v01 = *(const float2*)(sS + row * 66 + ci);
        float2 v23 = *(const float2*)(sS + row * 66 + ci + 2);
        float s0 = v01.x, s1 = v01.y, s2 = v23.x, s3 = v23.y;
        float mx = fmaxf(fmaxf(s0, s1), fmaxf(s2, s3));
#pragma unroll
        for (int off = 1; off < 16; off <<= 1) mx = fmaxf(mx, __shfl_xor(mx, off, 16));
        float e0 = __expf(s0 - mx), e1 = __expf(s1 - mx);
        float e2 = __expf(s2 - mx), e3 = __expf(s3 - mx);
        float sum = e0 + e1 + e2 + e3;
#pragma unroll
        for (int off = 1; off < 16; off <<= 1) sum += __shfl_xor(sum, off, 16);
        float inv = 1.0f / sum;
        *(uint2*)(sSup + row * 68 + ci) = pack4(e0 * inv, e1 * inv, e2 * inv, e3 * inv);
      }
      __syncthreads();  // B7
    }  // t

    // ---- write h_last for this layer (sHf is final h) ----
    {
      float* outp = OutH + (size_t)(layer * BB + b) * NH;
      int r = tid >> 4, c0 = (tid & 15) * 8;
      *(float4*)(outp + r * 128 + c0)     = *(const float4*)(sHf + r * 128 + c0);
      *(float4*)(outp + r * 128 + c0 + 4) = *(const float4*)(sHf + r * 128 + c0 + 4);
    }
    __syncthreads();
  }  // layer
}

extern "C" void kernel_launch(void* const* d_in, const int* in_sizes, int n_in,
                              void* d_out, int out_size, void* d_ws, size_t ws_size,
                              hipStream_t stream) {
  const float* Xin  = (const float*)d_in[0];
  const float* H0   = (const float*)d_in[1];
  const float* Sup0 = (const float*)d_in[2];
  const float* Wg0  = (const float*)d_in[3];
  const float* bg0  = (const float*)d_in[4];
  const float* Wc0  = (const float*)d_in[5];
  const float* bc0  = (const float*)d_in[6];
  const float* Wq0  = (const float*)d_in[7];
  const float* Wk0  = (const float*)d_in[8];
  const float* Wg1  = (const float*)d_in[9];
  const float* bg1  = (const float*)d_in[10];
  const float* Wc1  = (const float*)d_in[11];
  const float* bc1  = (const float*)d_in[12];
  const float* Wq1  = (const float*)d_in[13];
  const float* Wk1  = (const float*)d_in[14];
  unsigned short* Wp = (unsigned short*)d_ws;

  hipFuncSetAttribute(reinterpret_cast<const void*>(sglc_main),
                      hipFuncAttributeMaxDynamicSharedMemorySize, LDS_BYTES);

  hipLaunchKernelGGL(sglc_pack, dim3(1792), dim3(256), 0, stream,
                     Wg0, Wc0, Wq0, Wk0, Wg1, Wc1, Wq1, Wk1, Wp);
  hipLaunchKernelGGL(sglc_main, dim3(BB), dim3(1024), LDS_BYTES, stream,
                     Xin, H0, Sup0, bg0, bc0, bg1, bc1, Wp, (float*)d_out);
}